// Round 14
// baseline (213.810 us; speedup 1.0000x reference)
//
#include <hip/hip_runtime.h>

// Problem constants (fixed by setup_inputs): x (4, 64, 8192, 1) fp32, k=9, dilation=1
#define BB 4
#define DD 64
#define NN 8192
#define KK 9

// ---------------------------------------------------------------------------
// MFMA filter + exact rescan
//   K1 knorm2: normalize, emit fp32 xnT, sq, fp16 casts P=fp16(xn), S=fp16(-2xn)
//   K2 kmin:   fp16 MFMA GEMM -> per-(row, 16-j-group) min of approx -2*dot.
//              R12/R13: block's 4 waves share cooperatively-staged A-tiles
//              (XOR-swizzled LDS, ds_read_b128 consume). R14: depth-2 prefetch
//              with 3-buffer rotation — R13 post-mortem: depth-1 left part of
//              the ~500cy L2 load inside the 16x barrier-coupled per-tile path
//              (~5K cy/tile measured vs ~800 modeled). Now tile t+1's ds_write
//              uses data loaded >=1 full iteration earlier (vmcnt satisfied),
//              and tile t+3's load is issued at iter t (2 iterations of cover).
//              minbuf16 layout: s = jsplit*32 + half*16 + u (16 jsplits);
//              one full 64B line per row per block flush.
//   K3 ksel:   UNCHANGED (R8-R13: converged ~120us across 5 orthogonal nulls).
// Fallback to the original verified path if ws_size is too small.
// ---------------------------------------------------------------------------

typedef __attribute__((ext_vector_type(8))) _Float16 f16x8;  // 4 VGPR MFMA operand
typedef __attribute__((ext_vector_type(16))) float f32x16;   // 32x32 accumulator
typedef __attribute__((ext_vector_type(2))) _Float16 h2;     // v_dot2 operand
struct H2x4 { h2 a, b, c, d; };

__device__ __forceinline__ uint4 pack8(const unsigned* w) {
    return make_uint4(w[0] | (w[1] << 16), w[2] | (w[3] << 16),
                      w[4] | (w[5] << 16), w[6] | (w[7] << 16));
}

__device__ __forceinline__ float min3f(float a, float b, float c) {
    return fminf(fminf(a, b), c);            // clang fuses to v_min3_f32
}

__device__ __forceinline__ float dot2acc(h2 g, h2 r, float acc) {
#if __has_builtin(__builtin_amdgcn_fdot2)
    return __builtin_amdgcn_fdot2(g, r, acc, false);
#else
    acc = fmaf((float)g[0], (float)r[0], acc);
    return fmaf((float)g[1], (float)r[1], acc);
#endif
}

// storage-index -> j mapping: s = jsplit*32 + half*16 + u (16 jsplits, u in [0,16))
// tile T = jsplit*16 + u ; j = T*32 + (s4>>2)*8 + half*4 + (s4&3)
__device__ __forceinline__ int s_to_j(int g, int s4) {
    int T = ((g >> 5) << 4) + (g & 15);
    return (T << 5) + ((s4 >> 2) << 3) + (((g >> 4) & 1) << 2) + (s4 & 3);
}

// ---------------- K1: normalize + fp32 pack + sq + fp16 casts -----------------
__global__ __launch_bounds__(256) void knorm2_kernel(const float* __restrict__ x,
                                                     float* __restrict__ xnT,
                                                     float* __restrict__ sq,
                                                     unsigned short* __restrict__ Phi,
                                                     unsigned short* __restrict__ Shi) {
    int t = blockIdx.x * 256 + threadIdx.x;      // row id 0..B*N-1
    int b = t >> 13;
    int n = t & (NN - 1);
    const float* xb = x + (size_t)b * DD * NN + n;
    float v[DD];
    float ss = 0.0f;
#pragma unroll
    for (int d = 0; d < DD; ++d) {
        v[d] = xb[(size_t)d * NN];
        ss = fmaf(v[d], v[d], ss);
    }
    float inv = 1.0f / fmaxf(sqrtf(ss), 1e-12f);
    float s2 = 0.0f;
#pragma unroll
    for (int d = 0; d < DD; ++d) {
        v[d] *= inv;
        s2 = fmaf(v[d], v[d], s2);
    }
    sq[t] = s2;
    float4* o4 = reinterpret_cast<float4*>(xnT + (size_t)t * DD);
#pragma unroll
    for (int d = 0; d < DD; d += 4) o4[d >> 2] = make_float4(v[d], v[d+1], v[d+2], v[d+3]);

    size_t base = (size_t)t * DD;
#pragma unroll
    for (int d0 = 0; d0 < DD; d0 += 8) {
        unsigned ph[8], sh[8];
#pragma unroll
        for (int e = 0; e < 8; ++e) {
            float f = v[d0 + e];
            _Float16 hp = (_Float16)f;               // v_cvt_f16_f32 (RNE)
            _Float16 hs = (_Float16)(-2.0f * f);     // exact scale before rounding
            ph[e] = (unsigned)__builtin_bit_cast(unsigned short, hp);
            sh[e] = (unsigned)__builtin_bit_cast(unsigned short, hs);
        }
        *reinterpret_cast<uint4*>(Phi + base + d0) = pack8(ph);
        *reinterpret_cast<uint4*>(Shi + base + d0) = pack8(sh);
    }
}

// ---------------- K2: MFMA min pass (LDS-staged A, depth-2 prefetch) ---------
// Block = 4 waves x 64 i-rows = 256 rows; grid (128 rowblocks, 16 jsplits);
// 16 tiles/block, all 4 waves consume the SAME staged A-tile per step.
__global__ __launch_bounds__(256, 4) void kmin_kernel(const unsigned short* __restrict__ Shi,
                                                      const unsigned short* __restrict__ Phi,
                                                      unsigned short* __restrict__ minbuf16) {
    __shared__ unsigned short Ast[3][2048];              // 3 x 4KB A-tile (swizzled)
    __shared__ unsigned short stage[4][64][34];          // 17.4KB fp16 min-stage
    const int tid = threadIdx.x;
    const int lane = tid & 63;
    const int wave = tid >> 6;
    const int l31 = lane & 31;
    const int half = lane >> 5;
    const int i0 = blockIdx.x * 256 + wave * 64;         // global i-row base
    const int b = blockIdx.x >> 5;                       // batch (32 rowblocks each)
    const int jloc0 = blockIdx.y * 512;                  // batch-local j start
    const size_t jrow0 = (size_t)b * NN + jloc0;         // first global j-row

    // B fragments (two 32-row sets; 8 MFMA per staged tile)
    f16x8 Bh0[4], Bh1[4];
    {
        const size_t ib0 = (size_t)(i0 + l31) * DD + half * 8;
        const size_t ib1 = (size_t)(i0 + 32 + l31) * DD + half * 8;
#pragma unroll
        for (int kc = 0; kc < 4; ++kc) {
            Bh0[kc] = *reinterpret_cast<const f16x8*>(Phi + ib0 + kc * 16);
            Bh1[kc] = *reinterpret_cast<const f16x8*>(Phi + ib1 + kc * 16);
        }
    }

    // staging piece for this thread: row (of 32), 16B piece p (of 8)
    const int srow = tid >> 3;
    const int sp = tid & 7;
    const unsigned soff = (unsigned)(srow * 64 + ((sp * 8) ^ ((srow & 7) << 3)));
    const size_t gbase = (jrow0 + srow) * DD + sp * 8;

    // prologue: tile0 -> buf0; preload tiles 1,2 into registers
    uint4 gA, gB;
    {
        uint4 g0 = *reinterpret_cast<const uint4*>(Shi + gbase);
        *reinterpret_cast<uint4*>(&Ast[0][soff]) = g0;
        gA = *reinterpret_cast<const uint4*>(Shi + gbase + (size_t)1 * 32 * DD);
        gB = *reinterpret_cast<const uint4*>(Shi + gbase + (size_t)2 * 32 * DD);
    }
    __syncthreads();

#pragma unroll 1
    for (int t = 0; t < 16; ++t) {
        // consume staged tile buf[t%3]: 4 swizzled ds_read_b128 + 8 MFMA + mins
        const unsigned short* curb = &Ast[t % 3][0];
        f16x8 Ah[4];
#pragma unroll
        for (int kc = 0; kc < 4; ++kc) {
            unsigned off = (unsigned)(l31 * 64 + ((half * 8 + kc * 16) ^ ((l31 & 7) << 3)));
            Ah[kc] = *reinterpret_cast<const f16x8*>(&curb[off]);
        }
        f32x16 c0 = {}, c1 = {};
#pragma unroll
        for (int kc = 0; kc < 4; ++kc)
            c0 = __builtin_amdgcn_mfma_f32_32x32x16_f16(Ah[kc], Bh0[kc], c0, 0, 0, 0);
#pragma unroll
        for (int kc = 0; kc < 4; ++kc)
            c1 = __builtin_amdgcn_mfma_f32_32x32x16_f16(Ah[kc], Bh1[kc], c1, 0, 0, 0);
        const int col = half * 16 + t;
        {
            float q0 = min3f(c0[0], c0[1], c0[2]);
            float q1 = min3f(c0[3], c0[4], c0[5]);
            float q2 = min3f(c0[6], c0[7], c0[8]);
            float q3 = min3f(c0[9], c0[10], c0[11]);
            float q4 = min3f(c0[12], c0[13], c0[14]);
            float mv = fminf(min3f(q0, q1, q2), min3f(q3, q4, c0[15]));
            stage[wave][l31][col] = (unsigned short)__builtin_bit_cast(unsigned short, (_Float16)mv);
        }
        {
            float q0 = min3f(c1[0], c1[1], c1[2]);
            float q1 = min3f(c1[3], c1[4], c1[5]);
            float q2 = min3f(c1[6], c1[7], c1[8]);
            float q3 = min3f(c1[9], c1[10], c1[11]);
            float q4 = min3f(c1[12], c1[13], c1[14]);
            float mv = fminf(min3f(q0, q1, q2), min3f(q3, q4, c1[15]));
            stage[wave][32 + l31][col] = (unsigned short)__builtin_bit_cast(unsigned short, (_Float16)mv);
        }

        // ds_write tile t+1 from gA (load issued >=1 iteration ago — vmcnt
        // already satisfied, so the wait is off the barrier path), rotate,
        // and issue tile t+3's load (2 iterations of latency cover).
        // Hazards (3 buffers): write buf[(t+1)%3] at iter t vs prev reader
        // (tile t-2, iter t-2) = 2 barriers apart; vs next reader (iter t+1)
        // = 1 barrier. Both covered.
        if (t < 15)
            *reinterpret_cast<uint4*>(&Ast[(t + 1) % 3][soff]) = gA;
        gA = gB;
        if (t + 3 < 16)
            gB = *reinterpret_cast<const uint4*>(Shi + gbase + (size_t)(t + 3) * 32 * DD);
        __syncthreads();
    }

    // flush: one full 64B line per row: minbuf16[row*512 + blockIdx.y*32 .. +32]
    unsigned short* dst0 = minbuf16 + (size_t)blockIdx.y * 32;
#pragma unroll
    for (int it = 0; it < 4; ++it) {
        int idx = it * 64 + lane;                        // 0..255
        int r = idx >> 2;                                // 0..63
        int p = idx & 3;                                 // 16B piece (8 fp16)
        const unsigned* s32 = reinterpret_cast<const unsigned*>(&stage[wave][r][p * 8]);
        uint4 vv = make_uint4(s32[0], s32[1], s32[2], s32[3]);
        *reinterpret_cast<uint4*>(dst0 + (size_t)(i0 + r) * 512 + p * 8) = vv;
    }
}

// ---------------- K3: 2 rows per wave, interleaved chains (R11) --------------
__global__ __launch_bounds__(256) void ksel_kernel(const float* __restrict__ xnT,
                                                   const float* __restrict__ sq,
                                                   const unsigned short* __restrict__ minbuf16,
                                                   const unsigned short* __restrict__ Phi,
                                                   int* __restrict__ out) {
    __shared__ unsigned short glist[4][2][40];           // wave-private
    __shared__ unsigned short jlist[4][2][64];           // wave-private
    const int lane = threadIdx.x & 63;
    const int wave = threadIdx.x >> 6;
    const int tA = __builtin_amdgcn_readfirstlane(blockIdx.x * 8 + wave * 2);
    const int tB = tA + 1;
    const int b = tA >> 13;                              // pair shares batch (8|8192)
    const int nA = tA & (NN - 1);
    const int nB = tB & (NN - 1);

    float gmA[8], gmB[8];
    {
        uint4 a = *reinterpret_cast<const uint4*>(minbuf16 + (size_t)tA * 512 + lane * 8);
        uint4 c = *reinterpret_cast<const uint4*>(minbuf16 + (size_t)tB * 512 + lane * 8);
        unsigned wa[4] = {a.x, a.y, a.z, a.w};
        unsigned wb[4] = {c.x, c.y, c.z, c.w};
#pragma unroll
        for (int q4 = 0; q4 < 4; ++q4) {
            gmA[q4*2+0] = (float)__builtin_bit_cast(_Float16, (unsigned short)(wa[q4] & 0xFFFFu));
            gmA[q4*2+1] = (float)__builtin_bit_cast(_Float16, (unsigned short)(wa[q4] >> 16));
            gmB[q4*2+0] = (float)__builtin_bit_cast(_Float16, (unsigned short)(wb[q4] & 0xFFFFu));
            gmB[q4*2+1] = (float)__builtin_bit_cast(_Float16, (unsigned short)(wb[q4] >> 16));
        }
    }

    float svA = fminf(min3f(gmA[0], gmA[1], gmA[2]),
                      fminf(min3f(gmA[3], gmA[4], gmA[5]), fminf(gmA[6], gmA[7])));
    float svB = fminf(min3f(gmB[0], gmB[1], gmB[2]),
                      fminf(min3f(gmB[3], gmB[4], gmB[5]), fminf(gmB[6], gmB[7])));
#pragma unroll
    for (int k = 2; k <= 64; k <<= 1) {
#pragma unroll
        for (int jj = k >> 1; jj >= 1; jj >>= 1) {
            float oA = __shfl_xor(svA, jj);
            float oB = __shfl_xor(svB, jj);
            bool keepMin = (((lane & jj) == 0) == ((lane & k) == 0));
            svA = keepMin ? fminf(svA, oA) : fmaxf(svA, oA);
            svB = keepMin ? fminf(svB, oB) : fmaxf(svB, oB);
        }
    }
    const float th9pA = __shfl(svA, 8);
    const float th9pB = __shfl(svB, 8);
    const float thetaA  = th9pA + 8e-3f,  thetaB  = th9pB + 8e-3f;
    const float kappa1A = th9pA + 7.5e-3f, kappa1B = th9pB + 7.5e-3f;

    int cntA = 0, cntB = 0;
    unsigned short* glA = &glist[wave][0][0];
    unsigned short* glB = &glist[wave][1][0];
#pragma unroll
    for (int q = 0; q < 8; ++q) {
        bool cA = gmA[q] <= thetaA;
        unsigned long long mA = __ballot(cA);
        int pA = cntA + __popcll(mA & ((1ULL << lane) - 1ULL));
        if (cA && pA < 40) glA[pA] = (unsigned short)(lane * 8 + q);
        cntA += (int)__popcll(mA);
        bool cB = gmB[q] <= thetaB;
        unsigned long long mB = __ballot(cB);
        int pB = cntB + __popcll(mB & ((1ULL << lane) - 1ULL));
        if (cB && pB < 40) glB[pB] = (unsigned short)(lane * 8 + q);
        cntB += (int)__popcll(mB);
    }
    // no __syncthreads: lists are wave-private; within-wave LDS ordering is
    // program-order (block barrier would only couple the 4 waves).

    const unsigned short* __restrict__ Pb = Phi + ((size_t)b * NN) * DD;
    H2x4 arhA[8], arhB[8];
    {
        const f16x8* prA = reinterpret_cast<const f16x8*>(Phi + (size_t)tA * DD);
        const f16x8* prB = reinterpret_cast<const f16x8*>(Phi + (size_t)tB * DD);
#pragma unroll
        for (int c8 = 0; c8 < 8; ++c8) {
            arhA[c8] = __builtin_bit_cast(H2x4, prA[c8]);
            arhB[c8] = __builtin_bit_cast(H2x4, prB[c8]);
        }
    }

    const bool ovfA = (cntA > 40), ovfB = (cntB > 40);
    const int totalA = ovfA ? NN : cntA * 16;
    const int totalB = ovfB ? NN : cntB * 16;
    const int nItA = (totalA + 63) >> 6, nItB = (totalB + 63) >> 6;
    const int nIt = nItA > nItB ? nItA : nItB;
    int S1A = 0, S1B = 0;
    unsigned short* jlA = &jlist[wave][0][0];
    unsigned short* jlB = &jlist[wave][1][0];
#pragma unroll 1
    for (int m = 0; m < nIt; ++m) {
        const int idx = m * 64 + lane;
        const bool actA = idx < totalA;
        const bool actB = idx < totalB;
        float m2A = __uint_as_float(0x7f800000u);
        float m2B = __uint_as_float(0x7f800000u);
        int jA = 0, jB = 0;
        if (actA) {
            jA = ovfA ? idx : s_to_j((int)glA[idx >> 4], idx & 15);
            const f16x8* p8 = reinterpret_cast<const f16x8*>(Pb + (size_t)jA * DD);
            float a0 = 0.0f, a1 = 0.0f, a2 = 0.0f, a3 = 0.0f;
#pragma unroll
            for (int c8 = 0; c8 < 8; ++c8) {
                H2x4 g2 = __builtin_bit_cast(H2x4, p8[c8]);
                a0 = dot2acc(g2.a, arhA[c8].a, a0);
                a1 = dot2acc(g2.b, arhA[c8].b, a1);
                a2 = dot2acc(g2.c, arhA[c8].c, a2);
                a3 = dot2acc(g2.d, arhA[c8].d, a3);
            }
            m2A = -2.0f * ((a0 + a1) + (a2 + a3));
        }
        if (actB) {
            jB = ovfB ? idx : s_to_j((int)glB[idx >> 4], idx & 15);
            const f16x8* p8 = reinterpret_cast<const f16x8*>(Pb + (size_t)jB * DD);
            float a0 = 0.0f, a1 = 0.0f, a2 = 0.0f, a3 = 0.0f;
#pragma unroll
            for (int c8 = 0; c8 < 8; ++c8) {
                H2x4 g2 = __builtin_bit_cast(H2x4, p8[c8]);
                a0 = dot2acc(g2.a, arhB[c8].a, a0);
                a1 = dot2acc(g2.b, arhB[c8].b, a1);
                a2 = dot2acc(g2.c, arhB[c8].c, a2);
                a3 = dot2acc(g2.d, arhB[c8].d, a3);
            }
            m2B = -2.0f * ((a0 + a1) + (a2 + a3));
        }
        bool passA = actA && (m2A <= kappa1A);
        unsigned long long mA = __ballot(passA);
        int pA = S1A + __popcll(mA & ((1ULL << lane) - 1ULL));
        if (passA && pA < 64) jlA[pA] = (unsigned short)jA;
        S1A += (int)__popcll(mA);
        bool passB = actB && (m2B <= kappa1B);
        unsigned long long mB = __ballot(passB);
        int pB = S1B + __popcll(mB & ((1ULL << lane) - 1ULL));
        if (passB && pB < 64) jlB[pB] = (unsigned short)jB;
        S1B += (int)__popcll(mB);
    }

    const float* __restrict__ Bb = xnT + (size_t)b * NN * DD;
    const float* __restrict__ sqb = sq + (size_t)b * NN;

    unsigned long long vA = ~0ULL, vB = ~0ULL;
    {
        float4 bufA[4], bufB[4];
        int jA = 0, jB = 0;
        const bool hvA = lane < (S1A <= 64 ? S1A : 64);
        const bool hvB = lane < (S1B <= 64 ? S1B : 64);
        if (hvA) {
            jA = (int)jlA[lane];
            const float4* bc4 = reinterpret_cast<const float4*>(Bb + (size_t)jA * DD);
#pragma unroll
            for (int p = 0; p < 4; ++p) bufA[p] = bc4[p * 4];     // [0,4,8,12]
        }
        if (hvB) {
            jB = (int)jlB[lane];
            const float4* bc4 = reinterpret_cast<const float4*>(Bb + (size_t)jB * DD);
#pragma unroll
            for (int p = 0; p < 4; ++p) bufB[p] = bc4[p * 4];
        }
        {
            float ar[DD];
            const float4* a4 = reinterpret_cast<const float4*>(xnT + (size_t)tA * DD);
#pragma unroll
            for (int d = 0; d < DD; d += 4) {
                float4 f = a4[d >> 2];
                ar[d] = f.x; ar[d+1] = f.y; ar[d+2] = f.z; ar[d+3] = f.w;
            }
            if (hvA) {
                const float4* bc4 = reinterpret_cast<const float4*>(Bb + (size_t)jA * DD);
                float a0 = 0, a1 = 0, a2 = 0, a3 = 0;
#pragma unroll
                for (int d4 = 0; d4 < 16; ++d4) {
                    float4 f = (d4 % 4 == 0) ? bufA[d4 / 4] : bc4[d4];
                    a0 = fmaf(ar[4*d4+0], f.x, a0);
                    a1 = fmaf(ar[4*d4+1], f.y, a1);
                    a2 = fmaf(ar[4*d4+2], f.z, a2);
                    a3 = fmaf(ar[4*d4+3], f.w, a3);
                }
                float dot = (a0 + a1) + (a2 + a3);
                float key = fmaf(-2.0f, dot, sqb[jA]);   // byte-identical key
                unsigned ub = __float_as_uint(key);
                ub ^= (0x80000000u | (unsigned)((int)ub >> 31));
                vA = ((unsigned long long)ub << 32) | (unsigned)jA;
            }
        }
        {
            float ar[DD];
            const float4* a4 = reinterpret_cast<const float4*>(xnT + (size_t)tB * DD);
#pragma unroll
            for (int d = 0; d < DD; d += 4) {
                float4 f = a4[d >> 2];
                ar[d] = f.x; ar[d+1] = f.y; ar[d+2] = f.z; ar[d+3] = f.w;
            }
            if (hvB) {
                const float4* bc4 = reinterpret_cast<const float4*>(Bb + (size_t)jB * DD);
                float a0 = 0, a1 = 0, a2 = 0, a3 = 0;
#pragma unroll
                for (int d4 = 0; d4 < 16; ++d4) {
                    float4 f = (d4 % 4 == 0) ? bufB[d4 / 4] : bc4[d4];
                    a0 = fmaf(ar[4*d4+0], f.x, a0);
                    a1 = fmaf(ar[4*d4+1], f.y, a1);
                    a2 = fmaf(ar[4*d4+2], f.z, a2);
                    a3 = fmaf(ar[4*d4+3], f.w, a3);
                }
                float dot = (a0 + a1) + (a2 + a3);
                float key = fmaf(-2.0f, dot, sqb[jB]);
                unsigned ub = __float_as_uint(key);
                ub ^= (0x80000000u | (unsigned)((int)ub >> 31));
                vB = ((unsigned long long)ub << 32) | (unsigned)jB;
            }
        }
    }
#pragma unroll
    for (int k = 2; k <= 64; k <<= 1) {
#pragma unroll
        for (int jj = k >> 1; jj >= 1; jj >>= 1) {
            unsigned long long oA = __shfl_xor(vA, jj);
            unsigned long long oB = __shfl_xor(vB, jj);
            bool keepMin = (((lane & jj) == 0) == ((lane & k) == 0));
            {
                bool less = oA < vA;
                unsigned long long mn = less ? oA : vA;
                unsigned long long mx = less ? vA : oA;
                vA = keepMin ? mn : mx;
            }
            {
                bool less = oB < vB;
                unsigned long long mn = less ? oB : vB;
                unsigned long long mx = less ? vB : oB;
                vB = keepMin ? mn : mx;
            }
        }
    }
    unsigned long long koutA = vA, koutB = vB;

    auto exact_kd = [&](int tX, int totalX, bool ovfX,
                        const unsigned short* glX) -> unsigned long long {
        float ar[DD];
        const float4* a4 = reinterpret_cast<const float4*>(xnT + (size_t)tX * DD);
#pragma unroll
        for (int d = 0; d < DD; d += 4) {
            float4 f = a4[d >> 2];
            ar[d] = f.x; ar[d+1] = f.y; ar[d+2] = f.z; ar[d+3] = f.w;
        }
        unsigned long long kd[KK];
#pragma unroll
        for (int m = 0; m < KK; ++m) kd[m] = ~0ULL;
        const int nI = (totalX + 63) >> 6;
#pragma unroll 1
        for (int m = 0; m < nI; ++m) {
            const int idx = m * 64 + lane;
            if (idx >= totalX) continue;
            int j = ovfX ? idx : s_to_j((int)glX[idx >> 4], idx & 15);
            const float4* bc4 = reinterpret_cast<const float4*>(Bb + (size_t)j * DD);
            float a0 = 0, a1 = 0, a2 = 0, a3 = 0;
#pragma unroll
            for (int d4 = 0; d4 < 16; ++d4) {
                float4 f = bc4[d4];
                a0 = fmaf(ar[4*d4+0], f.x, a0);
                a1 = fmaf(ar[4*d4+1], f.y, a1);
                a2 = fmaf(ar[4*d4+2], f.z, a2);
                a3 = fmaf(ar[4*d4+3], f.w, a3);
            }
            float dot = (a0 + a1) + (a2 + a3);
            float key = fmaf(-2.0f, dot, sqb[j]);
            unsigned ub = __float_as_uint(key);
            ub ^= (0x80000000u | (unsigned)((int)ub >> 31));
            unsigned long long cnd = ((unsigned long long)ub << 32) | (unsigned)j;
            if (cnd < kd[KK - 1]) {
#pragma unroll
                for (int m2 = 0; m2 < KK; ++m2) {
                    bool sw = cnd < kd[m2];
                    unsigned long long lo = sw ? cnd : kd[m2];
                    unsigned long long hi = sw ? kd[m2] : cnd;
                    kd[m2] = lo;
                    cnd = hi;
                }
            }
        }
        unsigned long long ko = ~0ULL;
#pragma unroll
        for (int r = 0; r < KK; ++r) {
            unsigned long long c = kd[0];
            unsigned long long wm = c;
#pragma unroll
            for (int d = 1; d < 64; d <<= 1) {
                unsigned long long o = __shfl_xor(wm, d);
                wm = (o < wm) ? o : wm;
            }
            if (lane == r) ko = wm;
            if (c == wm) {
#pragma unroll
                for (int m2 = 0; m2 < KK - 1; ++m2) kd[m2] = kd[m2 + 1];
                kd[KK - 1] = ~0ULL;
            }
        }
        return ko;
    };
    if (S1A > 64) koutA = exact_kd(tA, totalA, ovfA, glA);
    if (S1B > 64) koutB = exact_kd(tB, totalB, ovfB, glB);

    if (lane < KK) {
        out[(size_t)tA * KK + lane] = (int)(koutA & 0xFFFFFFFFULL);
        out[(size_t)BB * NN * KK + (size_t)tA * KK + lane] = nA;
        out[(size_t)tB * KK + lane] = (int)(koutB & 0xFFFFFFFFULL);
        out[(size_t)BB * NN * KK + (size_t)tB * KK + lane] = nB;
    }
}

// ===========================================================================
// OLD PATH (verified fallback) -- unchanged
// ===========================================================================
__global__ __launch_bounds__(256) void knorm_kernel(const float* __restrict__ x,
                                                    float* __restrict__ xnT,
                                                    float* __restrict__ sq) {
    int t = blockIdx.x * 256 + threadIdx.x;
    int b = t >> 13;
    int n = t & (NN - 1);
    const float* xb = x + (size_t)b * DD * NN + n;
    float v[DD];
    float ss = 0.0f;
#pragma unroll
    for (int d = 0; d < DD; ++d) {
        v[d] = xb[(size_t)d * NN];
        ss = fmaf(v[d], v[d], ss);
    }
    float norm = sqrtf(ss);
    float inv = 1.0f / fmaxf(norm, 1e-12f);
    float s2 = 0.0f;
#pragma unroll
    for (int d = 0; d < DD; ++d) {
        float xv = v[d] * inv;
        v[d] = xv;
        s2 = fmaf(xv, xv, s2);
    }
    float4* o4 = reinterpret_cast<float4*>(xnT + (size_t)t * DD);
#pragma unroll
    for (int d = 0; d < DD; d += 4) {
        o4[d >> 2] = make_float4(v[d], v[d + 1], v[d + 2], v[d + 3]);
    }
    sq[t] = s2;
}

template <int S>
__global__ __launch_bounds__(256, 2) void kdist_kernel(const float* __restrict__ xnT,
                                                       const float* __restrict__ sq,
                                                       unsigned long long* __restrict__ cand) {
    const int rb = blockIdx.x;
    const int b = rb >> 5;
    const int nbase = (rb & 31) * 256;
    const int n = nbase + threadIdx.x;
    const int s = blockIdx.y;
    const int jcount = NN / S;
    const int j0 = s * jcount;
    const int j1 = j0 + jcount;

    const float* __restrict__ Bb = xnT + ((size_t)b * NN) * DD;
    const float* __restrict__ sqb = sq + (size_t)b * NN;

    float ar[DD];
    {
        const float4* a4 = reinterpret_cast<const float4*>(Bb + (size_t)n * DD);
#pragma unroll
        for (int d = 0; d < DD; d += 4) {
            float4 f = a4[d >> 2];
            ar[d] = f.x; ar[d + 1] = f.y; ar[d + 2] = f.z; ar[d + 3] = f.w;
        }
    }
#pragma unroll
    for (int d = 0; d < DD; ++d) {
        asm volatile("" : "+v"(ar[d]));
    }

    unsigned long long kd[KK];
#pragma unroll
    for (int m = 0; m < KK; ++m) kd[m] = ~0ULL;

#pragma unroll 2
    for (int j = j0; j < j1; ++j) {
        const float4* bc4 = reinterpret_cast<const float4*>(Bb + (size_t)j * DD);
        float a0 = 0.0f, a1 = 0.0f, a2 = 0.0f, a3 = 0.0f;
#pragma unroll
        for (int d4 = 0; d4 < DD / 4; ++d4) {
            float4 f = bc4[d4];
            a0 = fmaf(ar[4 * d4 + 0], f.x, a0);
            a1 = fmaf(ar[4 * d4 + 1], f.y, a1);
            a2 = fmaf(ar[4 * d4 + 2], f.z, a2);
            a3 = fmaf(ar[4 * d4 + 3], f.w, a3);
        }
        float dot = (a0 + a1) + (a2 + a3);
        float key = fmaf(-2.0f, dot, sqb[j]);
        unsigned int ub = __float_as_uint(key);
        ub ^= (0x80000000u | (unsigned int)((int)ub >> 31));
        unsigned long long cnd = ((unsigned long long)ub << 32) | (unsigned int)j;
        if (cnd < kd[KK - 1]) {
#pragma unroll
            for (int m = 0; m < KK; ++m) {
                bool sw = cnd < kd[m];
                unsigned long long lo = sw ? cnd : kd[m];
                unsigned long long hi = sw ? kd[m] : cnd;
                kd[m] = lo;
                cnd = hi;
            }
        }
    }

    unsigned long long* outc = cand + ((size_t)(b * NN + n) * S + s) * KK;
#pragma unroll
    for (int m = 0; m < KK; ++m) outc[m] = kd[m];
}

template <int S>
__global__ __launch_bounds__(256) void kmerge_kernel(const unsigned long long* __restrict__ cand,
                                                     int* __restrict__ out) {
    int t = blockIdx.x * 256 + threadIdx.x;
    const unsigned long long* c = cand + (size_t)t * (S * KK);
    unsigned long long kd[KK];
#pragma unroll
    for (int m = 0; m < KK; ++m) kd[m] = ~0ULL;
#pragma unroll
    for (int q = 0; q < S * KK; ++q) {
        unsigned long long cnd = c[q];
        if (cnd < kd[KK - 1]) {
#pragma unroll
            for (int m = 0; m < KK; ++m) {
                bool sw = cnd < kd[m];
                unsigned long long lo = sw ? cnd : kd[m];
                unsigned long long hi = sw ? kd[m] : cnd;
                kd[m] = lo;
                cnd = hi;
            }
        }
    }
    int n = t & (NN - 1);
    int* out0 = out + (size_t)t * KK;
    int* out1 = out + (size_t)BB * NN * KK + (size_t)t * KK;
#pragma unroll
    for (int m = 0; m < KK; ++m) {
        out0[m] = (int)(kd[m] & 0xFFFFFFFFULL);
        out1[m] = n;
    }
}

extern "C" void kernel_launch(void* const* d_in, const int* in_sizes, int n_in,
                              void* d_out, int out_size, void* d_ws, size_t ws_size,
                              hipStream_t stream) {
    const float* x = (const float*)d_in[0];
    int* out = (int*)d_out;
    char* ws = (char*)d_ws;

    // Shared layout head
    constexpr size_t XNT_B = (size_t)BB * NN * DD * 4;          //  8,388,608
    constexpr size_t SQ_B  = (size_t)BB * NN * 4;               //    131,072
    float* xnT = (float*)ws;
    float* sq  = (float*)(ws + XNT_B);

    // New-path layout (offsets kept from the verified R2 layout; Plo/Slo slots
    // unused but reserved so NEED_NEW is unchanged; minbuf fp16 = 32MB of the
    // 64MB reserved region)
    constexpr size_t BF_B  = (size_t)BB * NN * DD * 2;          //  4,194,304 each
    constexpr size_t OFF_PHI = XNT_B + SQ_B;
    constexpr size_t OFF_PLO = OFF_PHI + BF_B;
    constexpr size_t OFF_SHI = OFF_PLO + BF_B;
    constexpr size_t OFF_SLO = OFF_SHI + BF_B;
    constexpr size_t OFF_MIN = OFF_SLO + BF_B;
    constexpr size_t MIN_B   = (size_t)512 * BB * NN * 4;       // 67,108,864 (reserved)
    constexpr size_t NEED_NEW = OFF_MIN + MIN_B;                // 92,405,760

    if (ws_size >= NEED_NEW) {
        unsigned short* Phi = (unsigned short*)(ws + OFF_PHI);
        unsigned short* Shi = (unsigned short*)(ws + OFF_SHI);
        unsigned short* minbuf16 = (unsigned short*)(ws + OFF_MIN);

        knorm2_kernel<<<dim3(BB * NN / 256), dim3(256), 0, stream>>>(x, xnT, sq, Phi, Shi);
        kmin_kernel<<<dim3(BB * NN / 256, 16), dim3(256), 0, stream>>>(Shi, Phi, minbuf16);
        ksel_kernel<<<dim3(BB * NN / 8), dim3(256), 0, stream>>>(xnT, sq, minbuf16, Phi, out);
        return;
    }

    // Old verified path
    unsigned long long* cand = (unsigned long long*)(ws + XNT_B + SQ_B);
    const size_t base = XNT_B + SQ_B;
    const size_t need8 = base + (size_t)BB * NN * 8 * KK * 8;

    knorm_kernel<<<dim3(BB * NN / 256), dim3(256), 0, stream>>>(x, xnT, sq);
    if (ws_size >= need8) {
        kdist_kernel<8><<<dim3(BB * NN / 256, 8), dim3(256), 0, stream>>>(xnT, sq, cand);
        kmerge_kernel<8><<<dim3(BB * NN / 256), dim3(256), 0, stream>>>(cand, out);
    } else {
        kdist_kernel<4><<<dim3(BB * NN / 256, 4), dim3(256), 0, stream>>>(xnT, sq, cand);
        kmerge_kernel<4><<<dim3(BB * NN / 256), dim3(256), 0, stream>>>(cand, out);
    }
}

// Round 15
// 213.306 us; speedup vs baseline: 1.0024x; 1.0024x over previous
//
#include <hip/hip_runtime.h>

// Problem constants (fixed by setup_inputs): x (4, 64, 8192, 1) fp32, k=9, dilation=1
#define BB 4
#define DD 64
#define NN 8192
#define KK 9

// ---------------------------------------------------------------------------
// MFMA filter + exact rescan
//   K1 knorm2: normalize, emit fp32 xnT, sq, fp16 casts P=fp16(xn), S=fp16(-2xn)
//   K2 kmin:   fp16 MFMA GEMM -> per-(row,16-j-group) min of approx -2*dot.
//              LDS-staged shared A-tiles (R12/13), depth-2 prefetch (R14, ~null
//              but harmless). Parked: R9/R14 nulls => residual is barrier-
//              coupled MFMA/LDS serialization, counters unavailable (top-5
//              saturated by ksel).
//   K3 ksel:   2 rows/wave (R11). R15: stage-1 split into phase A (all j's +
//              all gathers issued + all m2's, fully unrolled, no cross-iter
//              deps -> loads pipeline) and phase B (ballot/compaction only).
//              The old loop serialized ~4 gather rounds through a FALSE dep
//              (ballot prefix), paying full gather latency per round. Fast
//              path gated wave-uniformly on cnt<=16; else the old serial loop
//              (identical output). arh loads hoisted to overlap the bitonic.
// Fallback to the original verified path if ws_size is too small.
// ---------------------------------------------------------------------------

typedef __attribute__((ext_vector_type(8))) _Float16 f16x8;  // 4 VGPR MFMA operand
typedef __attribute__((ext_vector_type(16))) float f32x16;   // 32x32 accumulator
typedef __attribute__((ext_vector_type(2))) _Float16 h2;     // v_dot2 operand
struct H2x4 { h2 a, b, c, d; };

__device__ __forceinline__ uint4 pack8(const unsigned* w) {
    return make_uint4(w[0] | (w[1] << 16), w[2] | (w[3] << 16),
                      w[4] | (w[5] << 16), w[6] | (w[7] << 16));
}

__device__ __forceinline__ float min3f(float a, float b, float c) {
    return fminf(fminf(a, b), c);            // clang fuses to v_min3_f32
}

__device__ __forceinline__ float dot2acc(h2 g, h2 r, float acc) {
#if __has_builtin(__builtin_amdgcn_fdot2)
    return __builtin_amdgcn_fdot2(g, r, acc, false);
#else
    acc = fmaf((float)g[0], (float)r[0], acc);
    return fmaf((float)g[1], (float)r[1], acc);
#endif
}

// storage-index -> j mapping: s = jsplit*32 + half*16 + u (16 jsplits, u in [0,16))
// tile T = jsplit*16 + u ; j = T*32 + (s4>>2)*8 + half*4 + (s4&3)
__device__ __forceinline__ int s_to_j(int g, int s4) {
    int T = ((g >> 5) << 4) + (g & 15);
    return (T << 5) + ((s4 >> 2) << 3) + (((g >> 4) & 1) << 2) + (s4 & 3);
}

// ---------------- K1: normalize + fp32 pack + sq + fp16 casts -----------------
__global__ __launch_bounds__(256) void knorm2_kernel(const float* __restrict__ x,
                                                     float* __restrict__ xnT,
                                                     float* __restrict__ sq,
                                                     unsigned short* __restrict__ Phi,
                                                     unsigned short* __restrict__ Shi) {
    int t = blockIdx.x * 256 + threadIdx.x;      // row id 0..B*N-1
    int b = t >> 13;
    int n = t & (NN - 1);
    const float* xb = x + (size_t)b * DD * NN + n;
    float v[DD];
    float ss = 0.0f;
#pragma unroll
    for (int d = 0; d < DD; ++d) {
        v[d] = xb[(size_t)d * NN];
        ss = fmaf(v[d], v[d], ss);
    }
    float inv = 1.0f / fmaxf(sqrtf(ss), 1e-12f);
    float s2 = 0.0f;
#pragma unroll
    for (int d = 0; d < DD; ++d) {
        v[d] *= inv;
        s2 = fmaf(v[d], v[d], s2);
    }
    sq[t] = s2;
    float4* o4 = reinterpret_cast<float4*>(xnT + (size_t)t * DD);
#pragma unroll
    for (int d = 0; d < DD; d += 4) o4[d >> 2] = make_float4(v[d], v[d+1], v[d+2], v[d+3]);

    size_t base = (size_t)t * DD;
#pragma unroll
    for (int d0 = 0; d0 < DD; d0 += 8) {
        unsigned ph[8], sh[8];
#pragma unroll
        for (int e = 0; e < 8; ++e) {
            float f = v[d0 + e];
            _Float16 hp = (_Float16)f;               // v_cvt_f16_f32 (RNE)
            _Float16 hs = (_Float16)(-2.0f * f);     // exact scale before rounding
            ph[e] = (unsigned)__builtin_bit_cast(unsigned short, hp);
            sh[e] = (unsigned)__builtin_bit_cast(unsigned short, hs);
        }
        *reinterpret_cast<uint4*>(Phi + base + d0) = pack8(ph);
        *reinterpret_cast<uint4*>(Shi + base + d0) = pack8(sh);
    }
}

// ---------------- K2: MFMA min pass (LDS-staged A, depth-2 prefetch) ---------
__global__ __launch_bounds__(256, 4) void kmin_kernel(const unsigned short* __restrict__ Shi,
                                                      const unsigned short* __restrict__ Phi,
                                                      unsigned short* __restrict__ minbuf16) {
    __shared__ unsigned short Ast[3][2048];              // 3 x 4KB A-tile (swizzled)
    __shared__ unsigned short stage[4][64][34];          // 17.4KB fp16 min-stage
    const int tid = threadIdx.x;
    const int lane = tid & 63;
    const int wave = tid >> 6;
    const int l31 = lane & 31;
    const int half = lane >> 5;
    const int i0 = blockIdx.x * 256 + wave * 64;         // global i-row base
    const int b = blockIdx.x >> 5;                       // batch (32 rowblocks each)
    const int jloc0 = blockIdx.y * 512;                  // batch-local j start
    const size_t jrow0 = (size_t)b * NN + jloc0;         // first global j-row

    f16x8 Bh0[4], Bh1[4];
    {
        const size_t ib0 = (size_t)(i0 + l31) * DD + half * 8;
        const size_t ib1 = (size_t)(i0 + 32 + l31) * DD + half * 8;
#pragma unroll
        for (int kc = 0; kc < 4; ++kc) {
            Bh0[kc] = *reinterpret_cast<const f16x8*>(Phi + ib0 + kc * 16);
            Bh1[kc] = *reinterpret_cast<const f16x8*>(Phi + ib1 + kc * 16);
        }
    }

    const int srow = tid >> 3;
    const int sp = tid & 7;
    const unsigned soff = (unsigned)(srow * 64 + ((sp * 8) ^ ((srow & 7) << 3)));
    const size_t gbase = (jrow0 + srow) * DD + sp * 8;

    uint4 gA, gB;
    {
        uint4 g0 = *reinterpret_cast<const uint4*>(Shi + gbase);
        *reinterpret_cast<uint4*>(&Ast[0][soff]) = g0;
        gA = *reinterpret_cast<const uint4*>(Shi + gbase + (size_t)1 * 32 * DD);
        gB = *reinterpret_cast<const uint4*>(Shi + gbase + (size_t)2 * 32 * DD);
    }
    __syncthreads();

#pragma unroll 1
    for (int t = 0; t < 16; ++t) {
        const unsigned short* curb = &Ast[t % 3][0];
        f16x8 Ah[4];
#pragma unroll
        for (int kc = 0; kc < 4; ++kc) {
            unsigned off = (unsigned)(l31 * 64 + ((half * 8 + kc * 16) ^ ((l31 & 7) << 3)));
            Ah[kc] = *reinterpret_cast<const f16x8*>(&curb[off]);
        }
        f32x16 c0 = {}, c1 = {};
#pragma unroll
        for (int kc = 0; kc < 4; ++kc)
            c0 = __builtin_amdgcn_mfma_f32_32x32x16_f16(Ah[kc], Bh0[kc], c0, 0, 0, 0);
#pragma unroll
        for (int kc = 0; kc < 4; ++kc)
            c1 = __builtin_amdgcn_mfma_f32_32x32x16_f16(Ah[kc], Bh1[kc], c1, 0, 0, 0);
        const int col = half * 16 + t;
        {
            float q0 = min3f(c0[0], c0[1], c0[2]);
            float q1 = min3f(c0[3], c0[4], c0[5]);
            float q2 = min3f(c0[6], c0[7], c0[8]);
            float q3 = min3f(c0[9], c0[10], c0[11]);
            float q4 = min3f(c0[12], c0[13], c0[14]);
            float mv = fminf(min3f(q0, q1, q2), min3f(q3, q4, c0[15]));
            stage[wave][l31][col] = (unsigned short)__builtin_bit_cast(unsigned short, (_Float16)mv);
        }
        {
            float q0 = min3f(c1[0], c1[1], c1[2]);
            float q1 = min3f(c1[3], c1[4], c1[5]);
            float q2 = min3f(c1[6], c1[7], c1[8]);
            float q3 = min3f(c1[9], c1[10], c1[11]);
            float q4 = min3f(c1[12], c1[13], c1[14]);
            float mv = fminf(min3f(q0, q1, q2), min3f(q3, q4, c1[15]));
            stage[wave][32 + l31][col] = (unsigned short)__builtin_bit_cast(unsigned short, (_Float16)mv);
        }

        if (t < 15)
            *reinterpret_cast<uint4*>(&Ast[(t + 1) % 3][soff]) = gA;
        gA = gB;
        if (t + 3 < 16)
            gB = *reinterpret_cast<const uint4*>(Shi + gbase + (size_t)(t + 3) * 32 * DD);
        __syncthreads();
    }

    unsigned short* dst0 = minbuf16 + (size_t)blockIdx.y * 32;
#pragma unroll
    for (int it = 0; it < 4; ++it) {
        int idx = it * 64 + lane;                        // 0..255
        int r = idx >> 2;                                // 0..63
        int p = idx & 3;                                 // 16B piece (8 fp16)
        const unsigned* s32 = reinterpret_cast<const unsigned*>(&stage[wave][r][p * 8]);
        uint4 vv = make_uint4(s32[0], s32[1], s32[2], s32[3]);
        *reinterpret_cast<uint4*>(dst0 + (size_t)(i0 + r) * 512 + p * 8) = vv;
    }
}

// ---------------- K3: 2 rows per wave, pipelined stage-1 (R15) ---------------
__global__ __launch_bounds__(256) void ksel_kernel(const float* __restrict__ xnT,
                                                   const float* __restrict__ sq,
                                                   const unsigned short* __restrict__ minbuf16,
                                                   const unsigned short* __restrict__ Phi,
                                                   int* __restrict__ out) {
    __shared__ unsigned short glist[4][2][40];           // wave-private
    __shared__ unsigned short jlist[4][2][64];           // wave-private
    const int lane = threadIdx.x & 63;
    const int wave = threadIdx.x >> 6;
    const int tA = __builtin_amdgcn_readfirstlane(blockIdx.x * 8 + wave * 2);
    const int tB = tA + 1;
    const int b = tA >> 13;                              // pair shares batch (8|8192)
    const int nA = tA & (NN - 1);
    const int nB = tB & (NN - 1);

    float gmA[8], gmB[8];
    {
        uint4 a = *reinterpret_cast<const uint4*>(minbuf16 + (size_t)tA * 512 + lane * 8);
        uint4 c = *reinterpret_cast<const uint4*>(minbuf16 + (size_t)tB * 512 + lane * 8);
        unsigned wa[4] = {a.x, a.y, a.z, a.w};
        unsigned wb[4] = {c.x, c.y, c.z, c.w};
#pragma unroll
        for (int q4 = 0; q4 < 4; ++q4) {
            gmA[q4*2+0] = (float)__builtin_bit_cast(_Float16, (unsigned short)(wa[q4] & 0xFFFFu));
            gmA[q4*2+1] = (float)__builtin_bit_cast(_Float16, (unsigned short)(wa[q4] >> 16));
            gmB[q4*2+0] = (float)__builtin_bit_cast(_Float16, (unsigned short)(wb[q4] & 0xFFFFu));
            gmB[q4*2+1] = (float)__builtin_bit_cast(_Float16, (unsigned short)(wb[q4] >> 16));
        }
    }

    // hoisted fp16 rows (wave-uniform -> scalar loads; overlap the bitonic)
    const unsigned short* __restrict__ Pb = Phi + ((size_t)b * NN) * DD;
    H2x4 arhA[8], arhB[8];
    {
        const f16x8* prA = reinterpret_cast<const f16x8*>(Phi + (size_t)tA * DD);
        const f16x8* prB = reinterpret_cast<const f16x8*>(Phi + (size_t)tB * DD);
#pragma unroll
        for (int c8 = 0; c8 < 8; ++c8) {
            arhA[c8] = __builtin_bit_cast(H2x4, prA[c8]);
            arhB[c8] = __builtin_bit_cast(H2x4, prB[c8]);
        }
    }

    float svA = fminf(min3f(gmA[0], gmA[1], gmA[2]),
                      fminf(min3f(gmA[3], gmA[4], gmA[5]), fminf(gmA[6], gmA[7])));
    float svB = fminf(min3f(gmB[0], gmB[1], gmB[2]),
                      fminf(min3f(gmB[3], gmB[4], gmB[5]), fminf(gmB[6], gmB[7])));
#pragma unroll
    for (int k = 2; k <= 64; k <<= 1) {
#pragma unroll
        for (int jj = k >> 1; jj >= 1; jj >>= 1) {
            float oA = __shfl_xor(svA, jj);
            float oB = __shfl_xor(svB, jj);
            bool keepMin = (((lane & jj) == 0) == ((lane & k) == 0));
            svA = keepMin ? fminf(svA, oA) : fmaxf(svA, oA);
            svB = keepMin ? fminf(svB, oB) : fmaxf(svB, oB);
        }
    }
    const float th9pA = __shfl(svA, 8);
    const float th9pB = __shfl(svB, 8);
    const float thetaA  = th9pA + 8e-3f,  thetaB  = th9pB + 8e-3f;
    const float kappa1A = th9pA + 7.5e-3f, kappa1B = th9pB + 7.5e-3f;

    int cntA = 0, cntB = 0;
    unsigned short* glA = &glist[wave][0][0];
    unsigned short* glB = &glist[wave][1][0];
#pragma unroll
    for (int q = 0; q < 8; ++q) {
        bool cA = gmA[q] <= thetaA;
        unsigned long long mA = __ballot(cA);
        int pA = cntA + __popcll(mA & ((1ULL << lane) - 1ULL));
        if (cA && pA < 40) glA[pA] = (unsigned short)(lane * 8 + q);
        cntA += (int)__popcll(mA);
        bool cB = gmB[q] <= thetaB;
        unsigned long long mB = __ballot(cB);
        int pB = cntB + __popcll(mB & ((1ULL << lane) - 1ULL));
        if (cB && pB < 40) glB[pB] = (unsigned short)(lane * 8 + q);
        cntB += (int)__popcll(mB);
    }
    // no __syncthreads: lists are wave-private; within-wave LDS ordering is
    // program-order.

    const bool ovfA = (cntA > 40), ovfB = (cntB > 40);
    const int totalA = ovfA ? NN : cntA * 16;
    const int totalB = ovfB ? NN : cntB * 16;
    int S1A = 0, S1B = 0;
    unsigned short* jlA = &jlist[wave][0][0];
    unsigned short* jlB = &jlist[wave][1][0];

    if (cntA <= 16 && cntB <= 16) {
        // ---- FAST PATH: phase A computes all j/m2 (gathers pipeline: no
        // cross-iteration deps); phase B does the ballot/compaction chain.
        int jAr[4], jBr[4];
        float m2Ar[4], m2Br[4];
#pragma unroll
        for (int m = 0; m < 4; ++m) {
            const int idx = m * 64 + lane;
            jAr[m] = 0; jBr[m] = 0;
            m2Ar[m] = __uint_as_float(0x7f800000u);
            m2Br[m] = __uint_as_float(0x7f800000u);
            if (idx < totalA) {
                int j = s_to_j((int)glA[idx >> 4], idx & 15);
                jAr[m] = j;
                const f16x8* p8 = reinterpret_cast<const f16x8*>(Pb + (size_t)j * DD);
                float a0 = 0.0f, a1 = 0.0f, a2 = 0.0f, a3 = 0.0f;
#pragma unroll
                for (int c8 = 0; c8 < 8; ++c8) {
                    H2x4 g2 = __builtin_bit_cast(H2x4, p8[c8]);
                    a0 = dot2acc(g2.a, arhA[c8].a, a0);
                    a1 = dot2acc(g2.b, arhA[c8].b, a1);
                    a2 = dot2acc(g2.c, arhA[c8].c, a2);
                    a3 = dot2acc(g2.d, arhA[c8].d, a3);
                }
                m2Ar[m] = -2.0f * ((a0 + a1) + (a2 + a3));
            }
            if (idx < totalB) {
                int j = s_to_j((int)glB[idx >> 4], idx & 15);
                jBr[m] = j;
                const f16x8* p8 = reinterpret_cast<const f16x8*>(Pb + (size_t)j * DD);
                float a0 = 0.0f, a1 = 0.0f, a2 = 0.0f, a3 = 0.0f;
#pragma unroll
                for (int c8 = 0; c8 < 8; ++c8) {
                    H2x4 g2 = __builtin_bit_cast(H2x4, p8[c8]);
                    a0 = dot2acc(g2.a, arhB[c8].a, a0);
                    a1 = dot2acc(g2.b, arhB[c8].b, a1);
                    a2 = dot2acc(g2.c, arhB[c8].c, a2);
                    a3 = dot2acc(g2.d, arhB[c8].d, a3);
                }
                m2Br[m] = -2.0f * ((a0 + a1) + (a2 + a3));
            }
        }
#pragma unroll
        for (int m = 0; m < 4; ++m) {
            bool passA = m2Ar[m] <= kappa1A;
            unsigned long long mA = __ballot(passA);
            int pA = S1A + __popcll(mA & ((1ULL << lane) - 1ULL));
            if (passA && pA < 64) jlA[pA] = (unsigned short)jAr[m];
            S1A += (int)__popcll(mA);
            bool passB = m2Br[m] <= kappa1B;
            unsigned long long mB = __ballot(passB);
            int pB = S1B + __popcll(mB & ((1ULL << lane) - 1ULL));
            if (passB && pB < 64) jlB[pB] = (unsigned short)jBr[m];
            S1B += (int)__popcll(mB);
        }
    } else {
        // ---- general path (any cnt, incl. overflow full-scan) -------------
        const int nItA = (totalA + 63) >> 6, nItB = (totalB + 63) >> 6;
        const int nIt = nItA > nItB ? nItA : nItB;
#pragma unroll 1
        for (int m = 0; m < nIt; ++m) {
            const int idx = m * 64 + lane;
            const bool actA = idx < totalA;
            const bool actB = idx < totalB;
            float m2A = __uint_as_float(0x7f800000u);
            float m2B = __uint_as_float(0x7f800000u);
            int jA = 0, jB = 0;
            if (actA) {
                jA = ovfA ? idx : s_to_j((int)glA[idx >> 4], idx & 15);
                const f16x8* p8 = reinterpret_cast<const f16x8*>(Pb + (size_t)jA * DD);
                float a0 = 0.0f, a1 = 0.0f, a2 = 0.0f, a3 = 0.0f;
#pragma unroll
                for (int c8 = 0; c8 < 8; ++c8) {
                    H2x4 g2 = __builtin_bit_cast(H2x4, p8[c8]);
                    a0 = dot2acc(g2.a, arhA[c8].a, a0);
                    a1 = dot2acc(g2.b, arhA[c8].b, a1);
                    a2 = dot2acc(g2.c, arhA[c8].c, a2);
                    a3 = dot2acc(g2.d, arhA[c8].d, a3);
                }
                m2A = -2.0f * ((a0 + a1) + (a2 + a3));
            }
            if (actB) {
                jB = ovfB ? idx : s_to_j((int)glB[idx >> 4], idx & 15);
                const f16x8* p8 = reinterpret_cast<const f16x8*>(Pb + (size_t)jB * DD);
                float a0 = 0.0f, a1 = 0.0f, a2 = 0.0f, a3 = 0.0f;
#pragma unroll
                for (int c8 = 0; c8 < 8; ++c8) {
                    H2x4 g2 = __builtin_bit_cast(H2x4, p8[c8]);
                    a0 = dot2acc(g2.a, arhB[c8].a, a0);
                    a1 = dot2acc(g2.b, arhB[c8].b, a1);
                    a2 = dot2acc(g2.c, arhB[c8].c, a2);
                    a3 = dot2acc(g2.d, arhB[c8].d, a3);
                }
                m2B = -2.0f * ((a0 + a1) + (a2 + a3));
            }
            bool passA = actA && (m2A <= kappa1A);
            unsigned long long mA = __ballot(passA);
            int pA = S1A + __popcll(mA & ((1ULL << lane) - 1ULL));
            if (passA && pA < 64) jlA[pA] = (unsigned short)jA;
            S1A += (int)__popcll(mA);
            bool passB = actB && (m2B <= kappa1B);
            unsigned long long mB = __ballot(passB);
            int pB = S1B + __popcll(mB & ((1ULL << lane) - 1ULL));
            if (passB && pB < 64) jlB[pB] = (unsigned short)jB;
            S1B += (int)__popcll(mB);
        }
    }

    const float* __restrict__ Bb = xnT + (size_t)b * NN * DD;
    const float* __restrict__ sqb = sq + (size_t)b * NN;

    unsigned long long vA = ~0ULL, vB = ~0ULL;
    {
        float4 bufA[4], bufB[4];
        int jA = 0, jB = 0;
        const bool hvA = lane < (S1A <= 64 ? S1A : 64);
        const bool hvB = lane < (S1B <= 64 ? S1B : 64);
        if (hvA) {
            jA = (int)jlA[lane];
            const float4* bc4 = reinterpret_cast<const float4*>(Bb + (size_t)jA * DD);
#pragma unroll
            for (int p = 0; p < 4; ++p) bufA[p] = bc4[p * 4];     // [0,4,8,12]
        }
        if (hvB) {
            jB = (int)jlB[lane];
            const float4* bc4 = reinterpret_cast<const float4*>(Bb + (size_t)jB * DD);
#pragma unroll
            for (int p = 0; p < 4; ++p) bufB[p] = bc4[p * 4];
        }
        {
            float ar[DD];
            const float4* a4 = reinterpret_cast<const float4*>(xnT + (size_t)tA * DD);
#pragma unroll
            for (int d = 0; d < DD; d += 4) {
                float4 f = a4[d >> 2];
                ar[d] = f.x; ar[d+1] = f.y; ar[d+2] = f.z; ar[d+3] = f.w;
            }
            if (hvA) {
                const float4* bc4 = reinterpret_cast<const float4*>(Bb + (size_t)jA * DD);
                float a0 = 0, a1 = 0, a2 = 0, a3 = 0;
#pragma unroll
                for (int d4 = 0; d4 < 16; ++d4) {
                    float4 f = (d4 % 4 == 0) ? bufA[d4 / 4] : bc4[d4];
                    a0 = fmaf(ar[4*d4+0], f.x, a0);
                    a1 = fmaf(ar[4*d4+1], f.y, a1);
                    a2 = fmaf(ar[4*d4+2], f.z, a2);
                    a3 = fmaf(ar[4*d4+3], f.w, a3);
                }
                float dot = (a0 + a1) + (a2 + a3);
                float key = fmaf(-2.0f, dot, sqb[jA]);   // byte-identical key
                unsigned ub = __float_as_uint(key);
                ub ^= (0x80000000u | (unsigned)((int)ub >> 31));
                vA = ((unsigned long long)ub << 32) | (unsigned)jA;
            }
        }
        {
            float ar[DD];
            const float4* a4 = reinterpret_cast<const float4*>(xnT + (size_t)tB * DD);
#pragma unroll
            for (int d = 0; d < DD; d += 4) {
                float4 f = a4[d >> 2];
                ar[d] = f.x; ar[d+1] = f.y; ar[d+2] = f.z; ar[d+3] = f.w;
            }
            if (hvB) {
                const float4* bc4 = reinterpret_cast<const float4*>(Bb + (size_t)jB * DD);
                float a0 = 0, a1 = 0, a2 = 0, a3 = 0;
#pragma unroll
                for (int d4 = 0; d4 < 16; ++d4) {
                    float4 f = (d4 % 4 == 0) ? bufB[d4 / 4] : bc4[d4];
                    a0 = fmaf(ar[4*d4+0], f.x, a0);
                    a1 = fmaf(ar[4*d4+1], f.y, a1);
                    a2 = fmaf(ar[4*d4+2], f.z, a2);
                    a3 = fmaf(ar[4*d4+3], f.w, a3);
                }
                float dot = (a0 + a1) + (a2 + a3);
                float key = fmaf(-2.0f, dot, sqb[jB]);
                unsigned ub = __float_as_uint(key);
                ub ^= (0x80000000u | (unsigned)((int)ub >> 31));
                vB = ((unsigned long long)ub << 32) | (unsigned)jB;
            }
        }
    }
#pragma unroll
    for (int k = 2; k <= 64; k <<= 1) {
#pragma unroll
        for (int jj = k >> 1; jj >= 1; jj >>= 1) {
            unsigned long long oA = __shfl_xor(vA, jj);
            unsigned long long oB = __shfl_xor(vB, jj);
            bool keepMin = (((lane & jj) == 0) == ((lane & k) == 0));
            {
                bool less = oA < vA;
                unsigned long long mn = less ? oA : vA;
                unsigned long long mx = less ? vA : oA;
                vA = keepMin ? mn : mx;
            }
            {
                bool less = oB < vB;
                unsigned long long mn = less ? oB : vB;
                unsigned long long mx = less ? vB : oB;
                vB = keepMin ? mn : mx;
            }
        }
    }
    unsigned long long koutA = vA, koutB = vB;

    auto exact_kd = [&](int tX, int totalX, bool ovfX,
                        const unsigned short* glX) -> unsigned long long {
        float ar[DD];
        const float4* a4 = reinterpret_cast<const float4*>(xnT + (size_t)tX * DD);
#pragma unroll
        for (int d = 0; d < DD; d += 4) {
            float4 f = a4[d >> 2];
            ar[d] = f.x; ar[d+1] = f.y; ar[d+2] = f.z; ar[d+3] = f.w;
        }
        unsigned long long kd[KK];
#pragma unroll
        for (int m = 0; m < KK; ++m) kd[m] = ~0ULL;
        const int nI = (totalX + 63) >> 6;
#pragma unroll 1
        for (int m = 0; m < nI; ++m) {
            const int idx = m * 64 + lane;
            if (idx >= totalX) continue;
            int j = ovfX ? idx : s_to_j((int)glX[idx >> 4], idx & 15);
            const float4* bc4 = reinterpret_cast<const float4*>(Bb + (size_t)j * DD);
            float a0 = 0, a1 = 0, a2 = 0, a3 = 0;
#pragma unroll
            for (int d4 = 0; d4 < 16; ++d4) {
                float4 f = bc4[d4];
                a0 = fmaf(ar[4*d4+0], f.x, a0);
                a1 = fmaf(ar[4*d4+1], f.y, a1);
                a2 = fmaf(ar[4*d4+2], f.z, a2);
                a3 = fmaf(ar[4*d4+3], f.w, a3);
            }
            float dot = (a0 + a1) + (a2 + a3);
            float key = fmaf(-2.0f, dot, sqb[j]);
            unsigned ub = __float_as_uint(key);
            ub ^= (0x80000000u | (unsigned)((int)ub >> 31));
            unsigned long long cnd = ((unsigned long long)ub << 32) | (unsigned)j;
            if (cnd < kd[KK - 1]) {
#pragma unroll
                for (int m2 = 0; m2 < KK; ++m2) {
                    bool sw = cnd < kd[m2];
                    unsigned long long lo = sw ? cnd : kd[m2];
                    unsigned long long hi = sw ? kd[m2] : cnd;
                    kd[m2] = lo;
                    cnd = hi;
                }
            }
        }
        unsigned long long ko = ~0ULL;
#pragma unroll
        for (int r = 0; r < KK; ++r) {
            unsigned long long c = kd[0];
            unsigned long long wm = c;
#pragma unroll
            for (int d = 1; d < 64; d <<= 1) {
                unsigned long long o = __shfl_xor(wm, d);
                wm = (o < wm) ? o : wm;
            }
            if (lane == r) ko = wm;
            if (c == wm) {
#pragma unroll
                for (int m2 = 0; m2 < KK - 1; ++m2) kd[m2] = kd[m2 + 1];
                kd[KK - 1] = ~0ULL;
            }
        }
        return ko;
    };
    if (S1A > 64) koutA = exact_kd(tA, totalA, ovfA, glA);
    if (S1B > 64) koutB = exact_kd(tB, totalB, ovfB, glB);

    if (lane < KK) {
        out[(size_t)tA * KK + lane] = (int)(koutA & 0xFFFFFFFFULL);
        out[(size_t)BB * NN * KK + (size_t)tA * KK + lane] = nA;
        out[(size_t)tB * KK + lane] = (int)(koutB & 0xFFFFFFFFULL);
        out[(size_t)BB * NN * KK + (size_t)tB * KK + lane] = nB;
    }
}

// ===========================================================================
// OLD PATH (verified fallback) -- unchanged
// ===========================================================================
__global__ __launch_bounds__(256) void knorm_kernel(const float* __restrict__ x,
                                                    float* __restrict__ xnT,
                                                    float* __restrict__ sq) {
    int t = blockIdx.x * 256 + threadIdx.x;
    int b = t >> 13;
    int n = t & (NN - 1);
    const float* xb = x + (size_t)b * DD * NN + n;
    float v[DD];
    float ss = 0.0f;
#pragma unroll
    for (int d = 0; d < DD; ++d) {
        v[d] = xb[(size_t)d * NN];
        ss = fmaf(v[d], v[d], ss);
    }
    float norm = sqrtf(ss);
    float inv = 1.0f / fmaxf(norm, 1e-12f);
    float s2 = 0.0f;
#pragma unroll
    for (int d = 0; d < DD; ++d) {
        float xv = v[d] * inv;
        v[d] = xv;
        s2 = fmaf(xv, xv, s2);
    }
    float4* o4 = reinterpret_cast<float4*>(xnT + (size_t)t * DD);
#pragma unroll
    for (int d = 0; d < DD; d += 4) {
        o4[d >> 2] = make_float4(v[d], v[d + 1], v[d + 2], v[d + 3]);
    }
    sq[t] = s2;
}

template <int S>
__global__ __launch_bounds__(256, 2) void kdist_kernel(const float* __restrict__ xnT,
                                                       const float* __restrict__ sq,
                                                       unsigned long long* __restrict__ cand) {
    const int rb = blockIdx.x;
    const int b = rb >> 5;
    const int nbase = (rb & 31) * 256;
    const int n = nbase + threadIdx.x;
    const int s = blockIdx.y;
    const int jcount = NN / S;
    const int j0 = s * jcount;
    const int j1 = j0 + jcount;

    const float* __restrict__ Bb = xnT + ((size_t)b * NN) * DD;
    const float* __restrict__ sqb = sq + (size_t)b * NN;

    float ar[DD];
    {
        const float4* a4 = reinterpret_cast<const float4*>(Bb + (size_t)n * DD);
#pragma unroll
        for (int d = 0; d < DD; d += 4) {
            float4 f = a4[d >> 2];
            ar[d] = f.x; ar[d + 1] = f.y; ar[d + 2] = f.z; ar[d + 3] = f.w;
        }
    }
#pragma unroll
    for (int d = 0; d < DD; ++d) {
        asm volatile("" : "+v"(ar[d]));
    }

    unsigned long long kd[KK];
#pragma unroll
    for (int m = 0; m < KK; ++m) kd[m] = ~0ULL;

#pragma unroll 2
    for (int j = j0; j < j1; ++j) {
        const float4* bc4 = reinterpret_cast<const float4*>(Bb + (size_t)j * DD);
        float a0 = 0.0f, a1 = 0.0f, a2 = 0.0f, a3 = 0.0f;
#pragma unroll
        for (int d4 = 0; d4 < DD / 4; ++d4) {
            float4 f = bc4[d4];
            a0 = fmaf(ar[4 * d4 + 0], f.x, a0);
            a1 = fmaf(ar[4 * d4 + 1], f.y, a1);
            a2 = fmaf(ar[4 * d4 + 2], f.z, a2);
            a3 = fmaf(ar[4 * d4 + 3], f.w, a3);
        }
        float dot = (a0 + a1) + (a2 + a3);
        float key = fmaf(-2.0f, dot, sqb[j]);
        unsigned int ub = __float_as_uint(key);
        ub ^= (0x80000000u | (unsigned int)((int)ub >> 31));
        unsigned long long cnd = ((unsigned long long)ub << 32) | (unsigned int)j;
        if (cnd < kd[KK - 1]) {
#pragma unroll
            for (int m = 0; m < KK; ++m) {
                bool sw = cnd < kd[m];
                unsigned long long lo = sw ? cnd : kd[m];
                unsigned long long hi = sw ? kd[m] : cnd;
                kd[m] = lo;
                cnd = hi;
            }
        }
    }

    unsigned long long* outc = cand + ((size_t)(b * NN + n) * S + s) * KK;
#pragma unroll
    for (int m = 0; m < KK; ++m) outc[m] = kd[m];
}

template <int S>
__global__ __launch_bounds__(256) void kmerge_kernel(const unsigned long long* __restrict__ cand,
                                                     int* __restrict__ out) {
    int t = blockIdx.x * 256 + threadIdx.x;
    const unsigned long long* c = cand + (size_t)t * (S * KK);
    unsigned long long kd[KK];
#pragma unroll
    for (int m = 0; m < KK; ++m) kd[m] = ~0ULL;
#pragma unroll
    for (int q = 0; q < S * KK; ++q) {
        unsigned long long cnd = c[q];
        if (cnd < kd[KK - 1]) {
#pragma unroll
            for (int m = 0; m < KK; ++m) {
                bool sw = cnd < kd[m];
                unsigned long long lo = sw ? cnd : kd[m];
                unsigned long long hi = sw ? kd[m] : cnd;
                kd[m] = lo;
                cnd = hi;
            }
        }
    }
    int n = t & (NN - 1);
    int* out0 = out + (size_t)t * KK;
    int* out1 = out + (size_t)BB * NN * KK + (size_t)t * KK;
#pragma unroll
    for (int m = 0; m < KK; ++m) {
        out0[m] = (int)(kd[m] & 0xFFFFFFFFULL);
        out1[m] = n;
    }
}

extern "C" void kernel_launch(void* const* d_in, const int* in_sizes, int n_in,
                              void* d_out, int out_size, void* d_ws, size_t ws_size,
                              hipStream_t stream) {
    const float* x = (const float*)d_in[0];
    int* out = (int*)d_out;
    char* ws = (char*)d_ws;

    // Shared layout head
    constexpr size_t XNT_B = (size_t)BB * NN * DD * 4;          //  8,388,608
    constexpr size_t SQ_B  = (size_t)BB * NN * 4;               //    131,072
    float* xnT = (float*)ws;
    float* sq  = (float*)(ws + XNT_B);

    // New-path layout (offsets kept from the verified R2 layout; Plo/Slo slots
    // unused but reserved so NEED_NEW is unchanged; minbuf fp16 = 32MB of the
    // 64MB reserved region)
    constexpr size_t BF_B  = (size_t)BB * NN * DD * 2;          //  4,194,304 each
    constexpr size_t OFF_PHI = XNT_B + SQ_B;
    constexpr size_t OFF_PLO = OFF_PHI + BF_B;
    constexpr size_t OFF_SHI = OFF_PLO + BF_B;
    constexpr size_t OFF_SLO = OFF_SHI + BF_B;
    constexpr size_t OFF_MIN = OFF_SLO + BF_B;
    constexpr size_t MIN_B   = (size_t)512 * BB * NN * 4;       // 67,108,864 (reserved)
    constexpr size_t NEED_NEW = OFF_MIN + MIN_B;                // 92,405,760

    if (ws_size >= NEED_NEW) {
        unsigned short* Phi = (unsigned short*)(ws + OFF_PHI);
        unsigned short* Shi = (unsigned short*)(ws + OFF_SHI);
        unsigned short* minbuf16 = (unsigned short*)(ws + OFF_MIN);

        knorm2_kernel<<<dim3(BB * NN / 256), dim3(256), 0, stream>>>(x, xnT, sq, Phi, Shi);
        kmin_kernel<<<dim3(BB * NN / 256, 16), dim3(256), 0, stream>>>(Shi, Phi, minbuf16);
        ksel_kernel<<<dim3(BB * NN / 8), dim3(256), 0, stream>>>(xnT, sq, minbuf16, Phi, out);
        return;
    }

    // Old verified path
    unsigned long long* cand = (unsigned long long*)(ws + XNT_B + SQ_B);
    const size_t base = XNT_B + SQ_B;
    const size_t need8 = base + (size_t)BB * NN * 8 * KK * 8;

    knorm_kernel<<<dim3(BB * NN / 256), dim3(256), 0, stream>>>(x, xnT, sq);
    if (ws_size >= need8) {
        kdist_kernel<8><<<dim3(BB * NN / 256, 8), dim3(256), 0, stream>>>(xnT, sq, cand);
        kmerge_kernel<8><<<dim3(BB * NN / 256), dim3(256), 0, stream>>>(cand, out);
    } else {
        kdist_kernel<4><<<dim3(BB * NN / 256, 4), dim3(256), 0, stream>>>(xnT, sq, cand);
        kmerge_kernel<4><<<dim3(BB * NN / 256), dim3(256), 0, stream>>>(cand, out);
    }
}